// Round 1
// baseline (172.096 us; speedup 1.0000x reference)
//
#include <hip/hip_runtime.h>

typedef __bf16 bf16x8 __attribute__((ext_vector_type(8)));
typedef float floatx16 __attribute__((ext_vector_type(16)));
typedef float floatx4 __attribute__((ext_vector_type(4)));

#define T_ 4096
#define STK 72      // LDS row stride in bf16 elems (64 + 8 pad)
#define NSPB 144    // split-blocks per batch: sum_{qt=0..31} ceil((qt+1)/4)

// ws layout (bytes)
#define WT_OFF 0u
#define Q_OFF  393216u
#define K_OFF  2490368u
#define V_OFF  4587520u
#define OP_OFF 6684672u
#define ML_OFF 25559040u

__device__ __forceinline__ unsigned short bf16bits(float f) {
  __bf16 h = (__bf16)f;
  return __builtin_bit_cast(unsigned short, h);
}

// ---------------- kernel 0: W -> W^T bf16, fold softmax scale into Wq ----------------
__global__ void wprep(const float* __restrict__ Wq, const float* __restrict__ Wk,
                      const float* __restrict__ Wv, __bf16* __restrict__ Wtg) {
  int idx = blockIdx.x * 256 + threadIdx.x;      // 0..196607
  int mat = idx >> 16;
  int r = idx & 65535;
  int h = r & 63;
  int k = r >> 6;
  const float* W = (mat == 0) ? Wq : ((mat == 1) ? Wk : Wv);
  float v = W[k * 64 + h];
  if (mat == 0) v *= 0.03125f * 1.4426950408889634f;  // C^-0.5 * log2(e)
  Wtg[(size_t)(mat * 64 + h) * 1024 + k] = (__bf16)v;
}

// ---------------- kernel 1: QKV projection (x fp32 -> Q~,K,V bf16) ----------------
__global__ __launch_bounds__(256, 3) void proj(const float* __restrict__ x,
                                               const __bf16* __restrict__ Wtg,
                                               __bf16* __restrict__ Qp,
                                               __bf16* __restrict__ Kp,
                                               __bf16* __restrict__ Vp) {
  __shared__ __align__(16) unsigned short sm[(64 + 192) * STK];
  unsigned short* xt = sm;              // [64 rows][STK]
  unsigned short* wt = sm + 64 * STK;   // [192 rows][STK]
  const int tid = threadIdx.x;
  const int wave = tid >> 6, lane = tid & 63;
  const int l15 = lane & 15, quad = lane >> 4;
  const size_t row0 = (size_t)blockIdx.x * 64;

  floatx4 acc[3][4];
#pragma unroll
  for (int m = 0; m < 3; m++)
#pragma unroll
    for (int t = 0; t < 4; t++)
#pragma unroll
      for (int i = 0; i < 4; i++) acc[m][t][i] = 0.0f;

  for (int kc = 0; kc < 16; ++kc) {
    __syncthreads();
    {  // stage x chunk [64][64] fp32 -> bf16
      int row = tid >> 2, seg = tid & 3;
      const float* src = x + (row0 + row) * 1024 + kc * 64 + seg * 16;
      float f[16];
      *(float4*)(f) = *(const float4*)(src);
      *(float4*)(f + 4) = *(const float4*)(src + 4);
      *(float4*)(f + 8) = *(const float4*)(src + 8);
      *(float4*)(f + 12) = *(const float4*)(src + 12);
      unsigned short hb[16];
#pragma unroll
      for (int i = 0; i < 16; i++) hb[i] = bf16bits(f[i]);
      *(uint4*)&xt[row * STK + seg * 16] = *(uint4*)(hb);
      *(uint4*)&xt[row * STK + seg * 16 + 8] = *(uint4*)(hb + 8);
    }
#pragma unroll
    for (int i = 0; i < 6; i++) {  // stage W^T chunk [192][64] bf16
      int idx = tid + 256 * i;
      int r = idx >> 3, c = (idx & 7) * 8;
      *(uint4*)&wt[r * STK + c] = *(const uint4*)(Wtg + (size_t)r * 1024 + kc * 64 + c);
    }
    __syncthreads();
#pragma unroll
    for (int ks = 0; ks < 2; ++ks) {
      bf16x8 a = *(const bf16x8*)&xt[(wave * 16 + l15) * STK + ks * 32 + quad * 8];
#pragma unroll
      for (int m = 0; m < 3; m++)
#pragma unroll
        for (int ht = 0; ht < 4; ++ht) {
          bf16x8 b = *(const bf16x8*)&wt[(m * 64 + ht * 16 + l15) * STK + ks * 32 + quad * 8];
          acc[m][ht] = __builtin_amdgcn_mfma_f32_16x16x32_bf16(a, b, acc[m][ht], 0, 0, 0);
        }
    }
  }
  // epilogue: C layout col=lane&15, row=quad*4+reg
#pragma unroll
  for (int m = 0; m < 3; m++) {
    __bf16* outp = (m == 0) ? Qp : ((m == 1) ? Kp : Vp);
#pragma unroll
    for (int ht = 0; ht < 4; ++ht)
#pragma unroll
      for (int r = 0; r < 4; r++) {
        size_t row = row0 + wave * 16 + quad * 4 + r;
        outp[row * 64 + ht * 16 + l15] = (__bf16)acc[m][ht][r];
      }
  }
}

// ---------------- kernel 2: flash attention pass 1 (split-K partials) ----------------
__global__ __launch_bounds__(256, 3) void attn1(const __bf16* __restrict__ Qp,
                                                const __bf16* __restrict__ Kp,
                                                const __bf16* __restrict__ Vp,
                                                float* __restrict__ Opart,
                                                float* __restrict__ mlpart) {
  __shared__ __align__(16) unsigned char smraw[36864];
  unsigned short* Kl = (unsigned short*)smraw;   // [64][STK]
  unsigned short* Vtl = Kl + 64 * STK;           // [64][STK] (V transposed: [h][key])
  unsigned short* Pl = Vtl + 64 * STK;           // [4 waves][32][STK]
  float* Oe = (float*)smraw;                     // epilogue reuse: [128][68]

  const int tid = threadIdx.x;
  const int wave = tid >> 6, lane = tid & 63;
  const int l31 = lane & 31, half = lane >> 5;

  const int bid = blockIdx.x;
  const int b = bid / NSPB;
  const int f = bid - b * NSPB;
  int qt = 0, cum = 0;
  for (;;) { int s = (qt + 4) >> 2; if (f < cum + s) break; cum += s; qt++; }
  const int si = f - cum;
  const int S = (qt + 4) >> 2;
  const int n_iters = 2 * (qt + 1);
  const int bbase = n_iters / S, rem = n_iters % S;
  const int it0 = si * bbase + (si < rem ? si : rem);
  const int it1 = it0 + bbase + (si < rem ? 1 : 0);

  const int qb = qt * 128;
  const size_t brow = (size_t)b * 4096;

  bf16x8 qf[4];
  {
    const __bf16* qptr = Qp + (brow + qb + wave * 32 + l31) * 64 + half * 8;
#pragma unroll
    for (int ks = 0; ks < 4; ks++) qf[ks] = *(const bf16x8*)(qptr + ks * 16);
  }

  floatx16 o0, o1;
#pragma unroll
  for (int r = 0; r < 16; r++) { o0[r] = 0.0f; o1[r] = 0.0f; }
  float m_run = -1e30f, l_run = 0.0f;
  unsigned short* Pw = Pl + wave * 32 * STK;
  const int qrow = qb + wave * 32 + l31;

  for (int it = it0; it < it1; ++it) {
    const int k0 = it * 64;
    // stage K [key][h]
#pragma unroll
    for (int i = 0; i < 2; i++) {
      int u = tid + 256 * i;
      int kr = u >> 3, c = (u & 7) * 8;
      *(uint4*)&Kl[kr * STK + c] = *(const uint4*)(Kp + (brow + k0 + kr) * 64 + c);
    }
    {  // stage V transposed -> Vtl[h][key]
      int kp = tid & 31, h0 = ((tid >> 5) & 7) * 8;
      const __bf16* vp = Vp + (brow + k0 + 2 * kp) * 64 + h0;
      unsigned short va[8], vb[8];
      *(uint4*)va = *(const uint4*)(vp);
      *(uint4*)vb = *(const uint4*)(vp + 64);
#pragma unroll
      for (int j = 0; j < 8; j++) {
        unsigned int w = (unsigned int)va[j] | ((unsigned int)vb[j] << 16);
        *(unsigned int*)&Vtl[(h0 + j) * STK + 2 * kp] = w;
      }
    }
    __syncthreads();
    // S^T = K @ Q^T  (m=key, n=q)
    floatx16 s0, s1;
#pragma unroll
    for (int r = 0; r < 16; r++) { s0[r] = 0.0f; s1[r] = 0.0f; }
#pragma unroll
    for (int ks = 0; ks < 4; ks++) {
      bf16x8 ka = *(const bf16x8*)&Kl[l31 * STK + ks * 16 + half * 8];
      bf16x8 kb = *(const bf16x8*)&Kl[(32 + l31) * STK + ks * 16 + half * 8];
      s0 = __builtin_amdgcn_mfma_f32_32x32x16_bf16(ka, qf[ks], s0, 0, 0, 0);
      s1 = __builtin_amdgcn_mfma_f32_32x32x16_bf16(kb, qf[ks], s1, 0, 0, 0);
    }
    if (k0 + 64 > qb) {  // diagonal: causal mask (key > q -> -inf)
#pragma unroll
      for (int r = 0; r < 16; r++) {
        int rs = (r & 3) + 8 * (r >> 2) + 4 * half;
        if (k0 + rs > qrow) s0[r] = -1e30f;
        if (k0 + 32 + rs > qrow) s1[r] = -1e30f;
      }
    }
    // online softmax: one q-row per lane (col=lane&31)
    float pm = -1e30f;
#pragma unroll
    for (int r = 0; r < 16; r++) { pm = fmaxf(pm, s0[r]); pm = fmaxf(pm, s1[r]); }
    pm = fmaxf(pm, __shfl_xor(pm, 32));
    float m_new = fmaxf(m_run, pm);
    float alpha = __builtin_amdgcn_exp2f(m_run - m_new);
    float psum = 0.0f;
#pragma unroll
    for (int r = 0; r < 16; r++) {
      s0[r] = __builtin_amdgcn_exp2f(s0[r] - m_new);
      s1[r] = __builtin_amdgcn_exp2f(s1[r] - m_new);
      psum += s0[r] + s1[r];
    }
    psum += __shfl_xor(psum, 32);
    l_run = l_run * alpha + psum;
    m_run = m_new;
#pragma unroll
    for (int r = 0; r < 16; r++) { o0[r] *= alpha; o1[r] *= alpha; }
    // P -> LDS [q][key] bf16 (4 consecutive keys per b64 write)
#pragma unroll
    for (int g = 0; g < 4; ++g) {
      int kb0 = 8 * g + 4 * half;
      unsigned int w0 = (unsigned int)bf16bits(s0[4 * g]) | ((unsigned int)bf16bits(s0[4 * g + 1]) << 16);
      unsigned int w1 = (unsigned int)bf16bits(s0[4 * g + 2]) | ((unsigned int)bf16bits(s0[4 * g + 3]) << 16);
      *(uint2*)&Pw[l31 * STK + kb0] = make_uint2(w0, w1);
      unsigned int w2 = (unsigned int)bf16bits(s1[4 * g]) | ((unsigned int)bf16bits(s1[4 * g + 1]) << 16);
      unsigned int w3 = (unsigned int)bf16bits(s1[4 * g + 2]) | ((unsigned int)bf16bits(s1[4 * g + 3]) << 16);
      *(uint2*)&Pw[l31 * STK + 32 + kb0] = make_uint2(w2, w3);
    }
    // O^T += V^T @ P^T  (m=h, n=q, k=key) — wave-private P, no barrier needed
#pragma unroll
    for (int kst = 0; kst < 4; ++kst) {
      bf16x8 pf = *(const bf16x8*)&Pw[l31 * STK + kst * 16 + half * 8];
      bf16x8 va = *(const bf16x8*)&Vtl[l31 * STK + kst * 16 + half * 8];
      bf16x8 vb = *(const bf16x8*)&Vtl[(32 + l31) * STK + kst * 16 + half * 8];
      o0 = __builtin_amdgcn_mfma_f32_32x32x16_bf16(va, pf, o0, 0, 0, 0);
      o1 = __builtin_amdgcn_mfma_f32_32x32x16_bf16(vb, pf, o1, 0, 0, 0);
    }
    __syncthreads();
  }
  // epilogue: transpose O^T -> Oe[q][h] in LDS, then coalesced partial store
#pragma unroll
  for (int r = 0; r < 16; r++) {
    int rs = (r & 3) + 8 * (r >> 2) + 4 * half;
    Oe[(wave * 32 + l31) * 68 + rs] = o0[r];
    Oe[(wave * 32 + l31) * 68 + 32 + rs] = o1[r];
  }
  if (lane < 32) {
    mlpart[(size_t)bid * 256 + wave * 32 + l31] = m_run;
    mlpart[(size_t)bid * 256 + 128 + wave * 32 + l31] = l_run;
  }
  __syncthreads();
  {
    float* dst = Opart + (size_t)bid * 8192;
    int r = tid >> 1, hh = (tid & 1) * 32;
#pragma unroll
    for (int i = 0; i < 8; i++)
      *(float4*)&dst[r * 64 + hh + 4 * i] = *(float4*)&Oe[r * 68 + hh + 4 * i];
  }
}

// ---------------- kernel 3: merge split partials, normalize ----------------
__global__ __launch_bounds__(256, 4) void attn2(const float* __restrict__ Opart,
                                                const float* __restrict__ mlpart,
                                                float* __restrict__ out) {
  const int bid = blockIdx.x;  // 0..511
  const int b = bid >> 7, rg = bid & 127;
  const int qt = rg >> 2;
  int cum = 0;
  for (int i = 0; i < qt; i++) cum += (i + 4) >> 2;
  const int S = (qt + 4) >> 2;
  const int t = threadIdx.x;
  const int r = t >> 3;
  const int prow = (rg & 3) * 32 + r;
  const int h0 = (t & 7) * 8;

  float M = -1e30f;
  for (int s = 0; s < S; s++)
    M = fmaxf(M, mlpart[(size_t)(b * NSPB + cum + s) * 256 + prow]);
  float a[8];
#pragma unroll
  for (int i = 0; i < 8; i++) a[i] = 0.0f;
  float L = 0.0f;
  for (int s = 0; s < S; s++) {
    size_t pb = (size_t)(b * NSPB + cum + s);
    float w = __builtin_amdgcn_exp2f(mlpart[pb * 256 + prow] - M);
    L += w * mlpart[pb * 256 + 128 + prow];
    const float* op = Opart + pb * 8192 + prow * 64 + h0;
    float4 v0 = *(const float4*)op;
    float4 v1 = *(const float4*)(op + 4);
    a[0] += w * v0.x; a[1] += w * v0.y; a[2] += w * v0.z; a[3] += w * v0.w;
    a[4] += w * v1.x; a[5] += w * v1.y; a[6] += w * v1.z; a[7] += w * v1.w;
  }
  float inv = 1.0f / L;
  float* po = out + ((size_t)b * 4096 + rg * 32 + r) * 64 + h0;
  float4 r0, r1;
  r0.x = a[0] * inv; r0.y = a[1] * inv; r0.z = a[2] * inv; r0.w = a[3] * inv;
  r1.x = a[4] * inv; r1.y = a[5] * inv; r1.z = a[6] * inv; r1.w = a[7] * inv;
  *(float4*)po = r0;
  *(float4*)(po + 4) = r1;
}

extern "C" void kernel_launch(void* const* d_in, const int* in_sizes, int n_in,
                              void* d_out, int out_size, void* d_ws, size_t ws_size,
                              hipStream_t stream) {
  (void)in_sizes; (void)n_in; (void)out_size; (void)ws_size;
  const float* x = (const float*)d_in[0];
  const float* Wq = (const float*)d_in[1];
  const float* Wk = (const float*)d_in[2];
  const float* Wv = (const float*)d_in[3];
  char* ws = (char*)d_ws;
  __bf16* Wtg = (__bf16*)(ws + WT_OFF);
  __bf16* Qp = (__bf16*)(ws + Q_OFF);
  __bf16* Kp = (__bf16*)(ws + K_OFF);
  __bf16* Vp = (__bf16*)(ws + V_OFF);
  float* Opart = (float*)(ws + OP_OFF);
  float* mlp = (float*)(ws + ML_OFF);
  float* out = (float*)d_out;

  hipLaunchKernelGGL(wprep, dim3(768), dim3(256), 0, stream, Wq, Wk, Wv, Wtg);
  hipLaunchKernelGGL(proj, dim3(256), dim3(256), 0, stream, x, Wtg, Qp, Kp, Vp);
  hipLaunchKernelGGL(attn1, dim3(4 * NSPB), dim3(256), 0, stream, Qp, Kp, Vp, Opart, mlp);
  hipLaunchKernelGGL(attn2, dim3(512), dim3(256), 0, stream, Opart, mlp, out);
}

// Round 2
// 148.948 us; speedup vs baseline: 1.1554x; 1.1554x over previous
//
#include <hip/hip_runtime.h>

typedef __bf16 bf16x8 __attribute__((ext_vector_type(8)));
typedef float floatx16 __attribute__((ext_vector_type(16)));
typedef float floatx4 __attribute__((ext_vector_type(4)));

#define T_ 4096
#define STK 72      // LDS row stride in bf16 elems (64 + 8 pad)
#define NSPB 144    // split-blocks per batch: sum_{qt=0..31} ceil((qt+1)/4)

// ws layout (bytes)
#define WT_OFF 0u
#define Q_OFF  393216u
#define K_OFF  2490368u
#define V_OFF  4587520u
#define OP_OFF 6684672u
#define ML_OFF 25559040u

__device__ __forceinline__ unsigned short bf16bits(float f) {
  __bf16 h = (__bf16)f;
  return __builtin_bit_cast(unsigned short, h);
}

// ---------------- kernel 0: W -> W^T bf16, fold softmax scale into Wq ----------------
__global__ void wprep(const float* __restrict__ Wq, const float* __restrict__ Wk,
                      const float* __restrict__ Wv, __bf16* __restrict__ Wtg) {
  int idx = blockIdx.x * 256 + threadIdx.x;      // 0..196607
  int mat = idx >> 16;
  int r = idx & 65535;
  int h = r & 63;
  int k = r >> 6;
  const float* W = (mat == 0) ? Wq : ((mat == 1) ? Wk : Wv);
  float v = W[k * 64 + h];
  if (mat == 0) v *= 0.03125f * 1.4426950408889634f;  // C^-0.5 * log2(e)
  Wtg[(size_t)(mat * 64 + h) * 1024 + k] = (__bf16)v;
}

// ---------------- kernel 1: QKV projection (x fp32 -> Q~,K,V bf16) ----------------
// 32 rows/block, 512 blocks -> 4 blocks/CU (LDS 32.3KB, VGPR ~52) for latency hiding.
// 4 waves = 2 M-tiles (16 rows) x 2 N-halves (96 cols = 6 ht-tiles).
__global__ __launch_bounds__(256, 4) void proj(const float* __restrict__ x,
                                               const __bf16* __restrict__ Wtg,
                                               __bf16* __restrict__ Qp,
                                               __bf16* __restrict__ Kp,
                                               __bf16* __restrict__ Vp) {
  __shared__ __align__(16) unsigned short sm[(32 + 192) * STK];
  unsigned short* xt = sm;              // [32 rows][STK]
  unsigned short* wt = sm + 32 * STK;   // [192 rows][STK]
  const int tid = threadIdx.x;
  const int wave = tid >> 6, lane = tid & 63;
  const int wm = wave & 1, wn = wave >> 1;
  const int l15 = lane & 15, quad = lane >> 4;
  const size_t row0 = (size_t)blockIdx.x * 32;

  floatx4 acc[6];
#pragma unroll
  for (int t = 0; t < 6; t++)
#pragma unroll
    for (int i = 0; i < 4; i++) acc[t][i] = 0.0f;

  for (int kc = 0; kc < 16; ++kc) {
    __syncthreads();
    {  // stage x chunk [32][64] fp32 -> bf16
      int row = tid >> 3, seg = tid & 7;
      const float* src = x + (row0 + row) * 1024 + kc * 64 + seg * 8;
      float f[8];
      *(float4*)(f) = *(const float4*)(src);
      *(float4*)(f + 4) = *(const float4*)(src + 4);
      unsigned short hb[8];
#pragma unroll
      for (int i = 0; i < 8; i++) hb[i] = bf16bits(f[i]);
      *(uint4*)&xt[row * STK + seg * 8] = *(uint4*)(hb);
    }
#pragma unroll
    for (int i = 0; i < 6; i++) {  // stage W^T chunk [192][64] bf16
      int idx = tid + 256 * i;
      int r = idx >> 3, c = (idx & 7) * 8;
      *(uint4*)&wt[r * STK + c] = *(const uint4*)(Wtg + (size_t)r * 1024 + kc * 64 + c);
    }
    __syncthreads();
#pragma unroll
    for (int ks = 0; ks < 2; ++ks) {
      bf16x8 a = *(const bf16x8*)&xt[(wm * 16 + l15) * STK + ks * 32 + quad * 8];
#pragma unroll
      for (int ht = 0; ht < 6; ++ht) {
        bf16x8 b = *(const bf16x8*)&wt[(wn * 96 + ht * 16 + l15) * STK + ks * 32 + quad * 8];
        acc[ht] = __builtin_amdgcn_mfma_f32_16x16x32_bf16(a, b, acc[ht], 0, 0, 0);
      }
    }
  }
  // epilogue: C layout col=lane&15, row=quad*4+reg
#pragma unroll
  for (int ht = 0; ht < 6; ++ht) {
    int g0 = wn * 96 + ht * 16;          // global output col base (0..191)
    int mat = g0 >> 6, h0 = g0 & 63;
    __bf16* outp = (mat == 0) ? Qp : ((mat == 1) ? Kp : Vp);
#pragma unroll
    for (int r = 0; r < 4; r++) {
      size_t row = row0 + wm * 16 + quad * 4 + r;
      outp[row * 64 + h0 + l15] = (__bf16)acc[ht][r];
    }
  }
}

// ---------------- kernel 2: flash attention pass 1 (split-K partials) ----------------
__global__ __launch_bounds__(256, 3) void attn1(const __bf16* __restrict__ Qp,
                                                const __bf16* __restrict__ Kp,
                                                const __bf16* __restrict__ Vp,
                                                float* __restrict__ Opart,
                                                float* __restrict__ mlpart) {
  __shared__ __align__(16) unsigned char smraw[36864];
  unsigned short* Kl = (unsigned short*)smraw;   // [64][STK]
  unsigned short* Vtl = Kl + 64 * STK;           // [64][STK] (V transposed: [h][key])
  unsigned short* Pl = Vtl + 64 * STK;           // [4 waves][32][STK]
  float* Oe = (float*)smraw;                     // epilogue reuse: [128][68]

  const int tid = threadIdx.x;
  const int wave = tid >> 6, lane = tid & 63;
  const int l31 = lane & 31, half = lane >> 5;

  const int bid = blockIdx.x;
  const int b = bid / NSPB;
  const int f = bid - b * NSPB;
  int qt = 0, cum = 0;
  for (;;) { int s = (qt + 4) >> 2; if (f < cum + s) break; cum += s; qt++; }
  const int si = f - cum;
  const int S = (qt + 4) >> 2;
  const int n_iters = 2 * (qt + 1);
  const int bbase = n_iters / S, rem = n_iters % S;
  const int it0 = si * bbase + (si < rem ? si : rem);
  const int it1 = it0 + bbase + (si < rem ? 1 : 0);

  const int qb = qt * 128;
  const size_t brow = (size_t)b * 4096;

  bf16x8 qf[4];
  {
    const __bf16* qptr = Qp + (brow + qb + wave * 32 + l31) * 64 + half * 8;
#pragma unroll
    for (int ks = 0; ks < 4; ks++) qf[ks] = *(const bf16x8*)(qptr + ks * 16);
  }

  floatx16 o0, o1;
#pragma unroll
  for (int r = 0; r < 16; r++) { o0[r] = 0.0f; o1[r] = 0.0f; }
  float m_run = -1e30f, l_run = 0.0f;
  unsigned short* Pw = Pl + wave * 32 * STK;
  const int qrow = qb + wave * 32 + l31;

  for (int it = it0; it < it1; ++it) {
    const int k0 = it * 64;
    // stage K [key][h]
#pragma unroll
    for (int i = 0; i < 2; i++) {
      int u = tid + 256 * i;
      int kr = u >> 3, c = (u & 7) * 8;
      *(uint4*)&Kl[kr * STK + c] = *(const uint4*)(Kp + (brow + k0 + kr) * 64 + c);
    }
    {  // stage V transposed -> Vtl[h][key]
      int kp = tid & 31, h0 = ((tid >> 5) & 7) * 8;
      const __bf16* vp = Vp + (brow + k0 + 2 * kp) * 64 + h0;
      unsigned short va[8], vb[8];
      *(uint4*)va = *(const uint4*)(vp);
      *(uint4*)vb = *(const uint4*)(vp + 64);
#pragma unroll
      for (int j = 0; j < 8; j++) {
        unsigned int w = (unsigned int)va[j] | ((unsigned int)vb[j] << 16);
        *(unsigned int*)&Vtl[(h0 + j) * STK + 2 * kp] = w;
      }
    }
    __syncthreads();
    // S^T = K @ Q^T  (m=key, n=q)
    floatx16 s0, s1;
#pragma unroll
    for (int r = 0; r < 16; r++) { s0[r] = 0.0f; s1[r] = 0.0f; }
#pragma unroll
    for (int ks = 0; ks < 4; ks++) {
      bf16x8 ka = *(const bf16x8*)&Kl[l31 * STK + ks * 16 + half * 8];
      bf16x8 kb = *(const bf16x8*)&Kl[(32 + l31) * STK + ks * 16 + half * 8];
      s0 = __builtin_amdgcn_mfma_f32_32x32x16_bf16(ka, qf[ks], s0, 0, 0, 0);
      s1 = __builtin_amdgcn_mfma_f32_32x32x16_bf16(kb, qf[ks], s1, 0, 0, 0);
    }
    if (k0 + 64 > qb) {  // diagonal: causal mask (key > q -> -inf)
#pragma unroll
      for (int r = 0; r < 16; r++) {
        int rs = (r & 3) + 8 * (r >> 2) + 4 * half;
        if (k0 + rs > qrow) s0[r] = -1e30f;
        if (k0 + 32 + rs > qrow) s1[r] = -1e30f;
      }
    }
    // online softmax: one q-row per lane (col=lane&31)
    float pm = -1e30f;
#pragma unroll
    for (int r = 0; r < 16; r++) { pm = fmaxf(pm, s0[r]); pm = fmaxf(pm, s1[r]); }
    pm = fmaxf(pm, __shfl_xor(pm, 32));
    float m_new = fmaxf(m_run, pm);
    float alpha = __builtin_amdgcn_exp2f(m_run - m_new);
    float psum = 0.0f;
#pragma unroll
    for (int r = 0; r < 16; r++) {
      s0[r] = __builtin_amdgcn_exp2f(s0[r] - m_new);
      s1[r] = __builtin_amdgcn_exp2f(s1[r] - m_new);
      psum += s0[r] + s1[r];
    }
    psum += __shfl_xor(psum, 32);
    l_run = l_run * alpha + psum;
    m_run = m_new;
#pragma unroll
    for (int r = 0; r < 16; r++) { o0[r] *= alpha; o1[r] *= alpha; }
    // P -> LDS [q][key] bf16 (4 consecutive keys per b64 write)
#pragma unroll
    for (int g = 0; g < 4; ++g) {
      int kb0 = 8 * g + 4 * half;
      unsigned int w0 = (unsigned int)bf16bits(s0[4 * g]) | ((unsigned int)bf16bits(s0[4 * g + 1]) << 16);
      unsigned int w1 = (unsigned int)bf16bits(s0[4 * g + 2]) | ((unsigned int)bf16bits(s0[4 * g + 3]) << 16);
      *(uint2*)&Pw[l31 * STK + kb0] = make_uint2(w0, w1);
      unsigned int w2 = (unsigned int)bf16bits(s1[4 * g]) | ((unsigned int)bf16bits(s1[4 * g + 1]) << 16);
      unsigned int w3 = (unsigned int)bf16bits(s1[4 * g + 2]) | ((unsigned int)bf16bits(s1[4 * g + 3]) << 16);
      *(uint2*)&Pw[l31 * STK + 32 + kb0] = make_uint2(w2, w3);
    }
    // O^T += V^T @ P^T  (m=h, n=q, k=key) — wave-private P, no barrier needed
#pragma unroll
    for (int kst = 0; kst < 4; ++kst) {
      bf16x8 pf = *(const bf16x8*)&Pw[l31 * STK + kst * 16 + half * 8];
      bf16x8 va = *(const bf16x8*)&Vtl[l31 * STK + kst * 16 + half * 8];
      bf16x8 vb = *(const bf16x8*)&Vtl[(32 + l31) * STK + kst * 16 + half * 8];
      o0 = __builtin_amdgcn_mfma_f32_32x32x16_bf16(va, pf, o0, 0, 0, 0);
      o1 = __builtin_amdgcn_mfma_f32_32x32x16_bf16(vb, pf, o1, 0, 0, 0);
    }
    __syncthreads();
  }
  // epilogue: transpose O^T -> Oe[q][h] in LDS, then coalesced partial store
#pragma unroll
  for (int r = 0; r < 16; r++) {
    int rs = (r & 3) + 8 * (r >> 2) + 4 * half;
    Oe[(wave * 32 + l31) * 68 + rs] = o0[r];
    Oe[(wave * 32 + l31) * 68 + 32 + rs] = o1[r];
  }
  if (lane < 32) {
    mlpart[(size_t)bid * 256 + wave * 32 + l31] = m_run;
    mlpart[(size_t)bid * 256 + 128 + wave * 32 + l31] = l_run;
  }
  __syncthreads();
  {
    float* dst = Opart + (size_t)bid * 8192;
    int r = tid >> 1, hh = (tid & 1) * 32;
#pragma unroll
    for (int i = 0; i < 8; i++)
      *(float4*)&dst[r * 64 + hh + 4 * i] = *(float4*)&Oe[r * 68 + hh + 4 * i];
  }
}

// ---------------- kernel 3: merge split partials, normalize ----------------
__global__ __launch_bounds__(256, 4) void attn2(const float* __restrict__ Opart,
                                                const float* __restrict__ mlpart,
                                                float* __restrict__ out) {
  const int bid = blockIdx.x;  // 0..511
  const int b = bid >> 7, rg = bid & 127;
  const int qt = rg >> 2;
  int cum = 0;
  for (int i = 0; i < qt; i++) cum += (i + 4) >> 2;
  const int S = (qt + 4) >> 2;
  const int t = threadIdx.x;
  const int r = t >> 3;
  const int prow = (rg & 3) * 32 + r;
  const int h0 = (t & 7) * 8;

  float M = -1e30f;
  for (int s = 0; s < S; s++)
    M = fmaxf(M, mlpart[(size_t)(b * NSPB + cum + s) * 256 + prow]);
  float a[8];
#pragma unroll
  for (int i = 0; i < 8; i++) a[i] = 0.0f;
  float L = 0.0f;
  for (int s = 0; s < S; s++) {
    size_t pb = (size_t)(b * NSPB + cum + s);
    float w = __builtin_amdgcn_exp2f(mlpart[pb * 256 + prow] - M);
    L += w * mlpart[pb * 256 + 128 + prow];
    const float* op = Opart + pb * 8192 + prow * 64 + h0;
    float4 v0 = *(const float4*)op;
    float4 v1 = *(const float4*)(op + 4);
    a[0] += w * v0.x; a[1] += w * v0.y; a[2] += w * v0.z; a[3] += w * v0.w;
    a[4] += w * v1.x; a[5] += w * v1.y; a[6] += w * v1.z; a[7] += w * v1.w;
  }
  float inv = 1.0f / L;
  float* po = out + ((size_t)b * 4096 + rg * 32 + r) * 64 + h0;
  float4 r0, r1;
  r0.x = a[0] * inv; r0.y = a[1] * inv; r0.z = a[2] * inv; r0.w = a[3] * inv;
  r1.x = a[4] * inv; r1.y = a[5] * inv; r1.z = a[6] * inv; r1.w = a[7] * inv;
  *(float4*)po = r0;
  *(float4*)(po + 4) = r1;
}

extern "C" void kernel_launch(void* const* d_in, const int* in_sizes, int n_in,
                              void* d_out, int out_size, void* d_ws, size_t ws_size,
                              hipStream_t stream) {
  (void)in_sizes; (void)n_in; (void)out_size; (void)ws_size;
  const float* x = (const float*)d_in[0];
  const float* Wq = (const float*)d_in[1];
  const float* Wk = (const float*)d_in[2];
  const float* Wv = (const float*)d_in[3];
  char* ws = (char*)d_ws;
  __bf16* Wtg = (__bf16*)(ws + WT_OFF);
  __bf16* Qp = (__bf16*)(ws + Q_OFF);
  __bf16* Kp = (__bf16*)(ws + K_OFF);
  __bf16* Vp = (__bf16*)(ws + V_OFF);
  float* Opart = (float*)(ws + OP_OFF);
  float* mlp = (float*)(ws + ML_OFF);
  float* out = (float*)d_out;

  hipLaunchKernelGGL(wprep, dim3(768), dim3(256), 0, stream, Wq, Wk, Wv, Wtg);
  hipLaunchKernelGGL(proj, dim3(512), dim3(256), 0, stream, x, Wtg, Qp, Kp, Vp);
  hipLaunchKernelGGL(attn1, dim3(4 * NSPB), dim3(256), 0, stream, Qp, Kp, Vp, Opart, mlp);
  hipLaunchKernelGGL(attn2, dim3(512), dim3(256), 0, stream, Opart, mlp, out);
}